// Round 1
// baseline (703.300 us; speedup 1.0000x reference)
//
#include <hip/hip_runtime.h>
#include <stdint.h>

#define LSEQ 32768
#define NCH 256      // scan chunks
#define TCH 128      // timesteps per chunk  (NCH*TCH == LSEQ)

typedef _Float16 half8 __attribute__((ext_vector_type(8)));
typedef _Float16 half4v __attribute__((ext_vector_type(4)));
typedef float f32x4 __attribute__((ext_vector_type(4)));

__device__ __forceinline__ float sigmoidf_(float x) { return 1.f / (1.f + __expf(-x)); }
__device__ __forceinline__ float gelu_(float x) {
    float z = 0.7978845608028654f * (x + 0.044715f * x * x * x);
    float e = __expf(2.f * z);
    float t = 1.f - 2.f / (e + 1.f);   // tanh(z)
    return 0.5f * x * (1.f + t);
}

// ---------------------------------------------------------------------------
// Generic fp16 MFMA GEMM core: C(BMxBN) = A(M x 256) @ Wt(N x 256)^T
// A row-major (K=256 contig), Wt row-major transposed weight (N rows, K contig).
// Block = 256 threads = 4 waves arranged WR x WC.
// LDS staged fragment-major: chunk(ks, r16) of 64 lanes x 16B, conflict-free b128.
// MFMA 16x16x32_f16 layout: Aop[m=lane&15][k=quad*8+j], Bop[k=quad*8+j][n=lane&15],
// D[row=quad*4+r][col=lane&15]  (learn_hip m89/m91-verified).
// ---------------------------------------------------------------------------
template <int BM, int BN, int WR, int WC>
__device__ __forceinline__ void gemm_core(const _Float16* __restrict__ A,
                                          const _Float16* __restrict__ Wt,
                                          _Float16* sA, _Float16* sW,
                                          int m0, int n0,
                                          f32x4 (&acc)[BM / (WR * 16)][BN / (WC * 16)]) {
    constexpr int MT = BM / (WR * 16);
    constexpr int NT = BN / (WC * 16);
    constexpr int CA = 2 * (BM / 16);
    constexpr int CW = 2 * (BN / 16);
    const int tid = threadIdx.x;
    const int wid = tid >> 6;
    const int lane = tid & 63;
    const int wm = wid / WC;
    const int wn = wid % WC;

    f32x4 zero = {0.f, 0.f, 0.f, 0.f};
#pragma unroll
    for (int i = 0; i < MT; ++i)
#pragma unroll
        for (int j = 0; j < NT; ++j) acc[i][j] = zero;

    for (int kb = 0; kb < 256; kb += 64) {
        __syncthreads();
#pragma unroll
        for (int i = 0; i < CA / 4; ++i) {
            int s = i * 256 + tid;
            int c = s >> 6, l = s & 63;
            int ks = c / (BM / 16), r16 = c % (BM / 16);
            const _Float16* gp = A + (m0 + r16 * 16 + (l & 15)) * 256 + kb + ks * 32 + (l >> 4) * 8;
            *(half8*)(sA + c * 512 + l * 8) = *(const half8*)gp;
        }
#pragma unroll
        for (int i = 0; i < CW / 4; ++i) {
            int s = i * 256 + tid;
            int c = s >> 6, l = s & 63;
            int ks = c / (BN / 16), n16 = c % (BN / 16);
            const _Float16* gp = Wt + (n0 + n16 * 16 + (l & 15)) * 256 + kb + ks * 32 + (l >> 4) * 8;
            *(half8*)(sW + c * 512 + l * 8) = *(const half8*)gp;
        }
        __syncthreads();
#pragma unroll
        for (int ks = 0; ks < 2; ++ks) {
            half8 af[MT], bf[NT];
#pragma unroll
            for (int mt = 0; mt < MT; ++mt)
                af[mt] = *(const half8*)(sA + (ks * (BM / 16) + wm * MT + mt) * 512 + lane * 8);
#pragma unroll
            for (int nt = 0; nt < NT; ++nt)
                bf[nt] = *(const half8*)(sW + (ks * (BN / 16) + wn * NT + nt) * 512 + lane * 8);
#pragma unroll
            for (int mt = 0; mt < MT; ++mt)
#pragma unroll
                for (int nt = 0; nt < NT; ++nt)
                    acc[mt][nt] = __builtin_amdgcn_mfma_f32_16x16x32_f16(af[mt], bf[nt], acc[mt][nt], 0, 0, 0);
        }
    }
    __syncthreads();
}

// --------------------------- setup kernels ---------------------------------
__global__ __launch_bounds__(512) void s5_k0a(const float* __restrict__ lre, const float* __restrict__ lim,
                                              const float* __restrict__ lstep,
                                              float* aR, float* aI, float* cbR, float* cbI,
                                              float* aTR, float* aTI, float* alp, float* ralp) {
    int i = threadIdx.x;  // 4 layers * 128 channels
    float st = expf(lstep[i]);
    float lr = lre[i] * st, li = lim[i] * st;
    float ea = expf(lr);
    float ar = ea * cosf(li), ai = ea * sinf(li);
    float den = lre[i] * lre[i] + lim[i] * lim[i];
    float nr = ar - 1.f, ni = ai;
    float cr = (nr * lre[i] + ni * lim[i]) / den;   // (a-1)/Lambda
    float ci = (ni * lre[i] - nr * lim[i]) / den;
    float cm = sqrtf(cr * cr + ci * ci);
    float al = sqrtf(2.83f / fmaxf(cm, 1e-8f));    // fp16 dynamic-range balancing
    float eT = expf(lr * (float)TCH);
    aR[i] = ar; aI[i] = ai;
    cbR[i] = cr; cbI[i] = ci;
    aTR[i] = eT * cosf(li * (float)TCH);
    aTI[i] = eT * sinf(li * (float)TCH);
    alp[i] = al; ralp[i] = 1.f / al;
}

__global__ __launch_bounds__(256) void s5_k0b(const float* __restrict__ Bre, const float* __restrict__ Bim,
                                              const float* __restrict__ Cre, const float* __restrict__ Cim,
                                              const float* __restrict__ W1, const float* __restrict__ W2,
                                              const float* __restrict__ b1, const float* __restrict__ b2,
                                              const float* __restrict__ Wout,
                                              const float* __restrict__ cbR, const float* __restrict__ cbI,
                                              const float* __restrict__ alp, const float* __restrict__ ralp,
                                              _Float16* Wbu, _Float16* Wc, _Float16* Wglu,
                                              _Float16* WoutT, float* bglu) {
    int stride = gridDim.x * blockDim.x;
    int tid0 = blockIdx.x * blockDim.x + threadIdx.x;
    // Wbu_t[l][n][k]: n<128: re(Bbar), else im(Bbar); scaled by alpha[channel]
    for (int i = tid0; i < 262144; i += stride) {
        int l = i >> 16, n = (i >> 8) & 255, k = i & 255;
        float v;
        if (n < 128) {
            int p = l * 128 + n;
            v = (cbR[p] * Bre[p * 256 + k] - cbI[p] * Bim[p * 256 + k]) * alp[p];
        } else {
            int p = l * 128 + n - 128;
            v = (cbR[p] * Bim[p * 256 + k] + cbI[p] * Bre[p * 256 + k]) * alp[p];
        }
        Wbu[i] = (_Float16)v;
    }
    // Wc_t[l][n][k]: k<128: 2*Cre[n][k], else -2*Cim[n][k-128]; scaled by 1/alpha
    for (int i = tid0; i < 262144; i += stride) {
        int l = i >> 16, n = (i >> 8) & 255, k = i & 255;
        float base = (k < 128) ? 2.f * Cre[(l * 256 + n) * 128 + k]
                               : -2.f * Cim[(l * 256 + n) * 128 + (k - 128)];
        Wc[i] = (_Float16)(base * ralp[l * 128 + (k & 127)]);
    }
    // Wglu_t[l][n][k]: interleaved cols: n even->W1[:,n/2], odd->W2[:,n/2]
    for (int i = tid0; i < 524288; i += stride) {
        int l = i >> 17, n = (i >> 8) & 511, k = i & 255;
        int j = n >> 1;
        const float* src = (n & 1) ? W2 : W1;
        Wglu[i] = (_Float16)src[(l * 256 + k) * 256 + j];
    }
    for (int i = tid0; i < 16384; i += stride) {
        int n = i >> 8, k = i & 255;
        WoutT[i] = (_Float16)Wout[k * 64 + n];
    }
    for (int i = tid0; i < 2048; i += stride) {
        int l = i >> 9, n = i & 511;
        bglu[i] = ((n & 1) ? b2 : b1)[l * 256 + (n >> 1)];
    }
}

__global__ __launch_bounds__(256) void s5_k0c(const float* __restrict__ latent, const float* __restrict__ W,
                                              const float* __restrict__ b, float* __restrict__ x0) {
    __shared__ float lat[256];
    lat[threadIdx.x] = latent[threadIdx.x];
    __syncthreads();
    float s = b[threadIdx.x];
    for (int k = 0; k < 256; ++k) s += lat[k] * W[k * 256 + threadIdx.x];
    x0[threadIdx.x] = (s > 0.f) ? s : 0.01f * s;   // leaky_relu
}

__global__ __launch_bounds__(256) void s5_k1_fill(const float* __restrict__ x0, float* __restrict__ x) {
    int i = blockIdx.x * 256 + threadIdx.x;       // 8192 blocks: L*256/4 float4s
    f32x4 v = *(const f32x4*)(x0 + (i & 63) * 4);
    *(f32x4*)(x + i * 4) = v;
}

// --------------------------- per-layer kernels -----------------------------
__global__ __launch_bounds__(256) void s5_k2_ln(const float* __restrict__ x, const float* __restrict__ gamma,
                                                const float* __restrict__ beta, _Float16* __restrict__ h) {
    int wid = threadIdx.x >> 6, lane = threadIdx.x & 63;
    int row = blockIdx.x * 4 + wid;
    const float* xr = x + row * 256;
    f32x4 v = *(const f32x4*)(xr + lane * 4);
    float s1 = v[0] + v[1] + v[2] + v[3];
    float s2 = v[0] * v[0] + v[1] * v[1] + v[2] * v[2] + v[3] * v[3];
#pragma unroll
    for (int off = 1; off < 64; off <<= 1) {
        s1 += __shfl_xor(s1, off, 64);
        s2 += __shfl_xor(s2, off, 64);
    }
    float mu = s1 * (1.f / 256.f);
    float var = s2 * (1.f / 256.f) - mu * mu;
    float rs = rsqrtf(fmaxf(var, 0.f) + 1e-6f);
    f32x4 g4 = *(const f32x4*)(gamma + lane * 4);
    f32x4 b4 = *(const f32x4*)(beta + lane * 4);
    half4v o;
#pragma unroll
    for (int j = 0; j < 4; ++j) o[j] = (_Float16)((v[j] - mu) * rs * g4[j] + b4[j]);
    *(half4v*)(h + row * 256 + lane * 4) = o;
}

__global__ __launch_bounds__(256) void s5_k3_gemm_bu(const _Float16* __restrict__ A,
                                                     const _Float16* __restrict__ Wt,
                                                     float* __restrict__ Bu) {
    __shared__ _Float16 sA[128 * 64], sW[128 * 64];
    f32x4 acc[4][4];
    int m0 = blockIdx.x * 128, n0 = blockIdx.y * 128;
    gemm_core<128, 128, 2, 2>(A, Wt, sA, sW, m0, n0, acc);
    int tid = threadIdx.x, wid = tid >> 6, lane = tid & 63, lm = lane & 15, quad = lane >> 4;
    int wm = wid >> 1, wn = wid & 1;
#pragma unroll
    for (int mt = 0; mt < 4; ++mt)
#pragma unroll
        for (int nt = 0; nt < 4; ++nt) {
            int col = n0 + wn * 64 + nt * 16 + lm;
#pragma unroll
            for (int r = 0; r < 4; ++r) {
                int row = m0 + wm * 64 + mt * 16 + quad * 4 + r;
                Bu[row * 256 + col] = acc[mt][nt][r];
            }
        }
}

__global__ __launch_bounds__(128) void s5_k4_scan(const float* __restrict__ Bu,
                                                  const float* __restrict__ aR, const float* __restrict__ aI,
                                                  _Float16* __restrict__ xsh,
                                                  float* __restrict__ carR, float* __restrict__ carI) {
    int p = threadIdx.x, c = blockIdx.x;
    float ar = aR[p], ai = aI[p];
    float sr = 0.f, si = 0.f;
    int t0 = c * TCH;
#pragma unroll 4
    for (int j = 0; j < TCH; ++j) {
        int t = t0 + j;
        float br = Bu[t * 256 + p], bi = Bu[t * 256 + p + 128];
        float nr = fmaf(ar, sr, fmaf(-ai, si, br));
        float ni = fmaf(ar, si, fmaf(ai, sr, bi));
        sr = nr; si = ni;
        xsh[t * 256 + p] = (_Float16)sr;
        xsh[t * 256 + p + 128] = (_Float16)si;
    }
    carR[c * 128 + p] = sr;
    carI[c * 128 + p] = si;
}

__global__ __launch_bounds__(128) void s5_k5_carry(const float* __restrict__ carR, const float* __restrict__ carI,
                                                   const float* __restrict__ aTR, const float* __restrict__ aTI,
                                                   float* __restrict__ cinR, float* __restrict__ cinI) {
    int p = threadIdx.x;
    float ar = aTR[p], ai = aTI[p];
    float rr = 0.f, ri = 0.f;
#pragma unroll 8
    for (int c = 0; c < NCH; ++c) {
        cinR[c * 128 + p] = rr;
        cinI[c * 128 + p] = ri;
        float cr = carR[c * 128 + p], ci = carI[c * 128 + p];
        float nr = fmaf(ar, rr, fmaf(-ai, ri, cr));
        float ni = fmaf(ar, ri, fmaf(ai, rr, ci));
        rr = nr; ri = ni;
    }
}

__global__ __launch_bounds__(128) void s5_k6_apply(const _Float16* __restrict__ xsh,
                                                   const float* __restrict__ cinR, const float* __restrict__ cinI,
                                                   const float* __restrict__ aR, const float* __restrict__ aI,
                                                   _Float16* __restrict__ xs2) {
    int p = threadIdx.x, c = blockIdx.x;
    float ar = aR[p], ai = aI[p];
    float cr = cinR[c * 128 + p], ci = cinI[c * 128 + p];
    float fr = ar, fi = ai;       // a^(j+1)
    int t0 = c * TCH;
#pragma unroll 4
    for (int j = 0; j < TCH; ++j) {
        int t = t0 + j;
        float xr = (float)xsh[t * 256 + p] + fr * cr - fi * ci;
        float xi = (float)xsh[t * 256 + p + 128] + fr * ci + fi * cr;
        xs2[t * 256 + p] = (_Float16)xr;
        xs2[t * 256 + p + 128] = (_Float16)xi;
        float nr = fr * ar - fi * ai, ni = fr * ai + fi * ar;
        fr = nr; fi = ni;
    }
}

__global__ __launch_bounds__(256) void s5_k7_gemm_c(const _Float16* __restrict__ A,
                                                    const _Float16* __restrict__ Wt,
                                                    const _Float16* __restrict__ h,
                                                    const float* __restrict__ Dv,
                                                    const float* __restrict__ gamma,
                                                    const float* __restrict__ beta,
                                                    _Float16* __restrict__ g) {
    __shared__ _Float16 sA[64 * 64], sW[256 * 64];
    __shared__ float red1[64][4], red2[64][4], mu_s[64], rs_s[64];
    f32x4 acc[4][4];
    int m0 = blockIdx.x * 64;
    gemm_core<64, 256, 1, 4>(A, Wt, sA, sW, m0, 0, acc);
    int tid = threadIdx.x, wid = tid >> 6, lane = tid & 63, lm = lane & 15, quad = lane >> 4;
    int wn = wid;
    // y = xs@Wc + h*D
#pragma unroll
    for (int nt = 0; nt < 4; ++nt) {
        int col = wn * 64 + nt * 16 + lm;
        float dv = Dv[col];
#pragma unroll
        for (int mt = 0; mt < 4; ++mt)
#pragma unroll
            for (int r = 0; r < 4; ++r) {
                int row = m0 + mt * 16 + quad * 4 + r;
                acc[mt][nt][r] += (float)h[row * 256 + col] * dv;
            }
    }
    // row stats (LN over 256 cols spread over 4 waves x 4 nt x 16 lanes)
    float s1[4][4], s2[4][4];
#pragma unroll
    for (int mt = 0; mt < 4; ++mt)
#pragma unroll
        for (int r = 0; r < 4; ++r) {
            float a = 0.f, b = 0.f;
#pragma unroll
            for (int nt = 0; nt < 4; ++nt) {
                float v = acc[mt][nt][r];
                a += v; b += v * v;
            }
#pragma unroll
            for (int off = 1; off < 16; off <<= 1) {
                a += __shfl_xor(a, off, 64);
                b += __shfl_xor(b, off, 64);
            }
            s1[mt][r] = a; s2[mt][r] = b;
        }
    if (lm == 0) {
#pragma unroll
        for (int mt = 0; mt < 4; ++mt)
#pragma unroll
            for (int r = 0; r < 4; ++r) {
                int row = mt * 16 + quad * 4 + r;
                red1[row][wid] = s1[mt][r];
                red2[row][wid] = s2[mt][r];
            }
    }
    __syncthreads();
    if (tid < 64) {
        float a = red1[tid][0] + red1[tid][1] + red1[tid][2] + red1[tid][3];
        float b = red2[tid][0] + red2[tid][1] + red2[tid][2] + red2[tid][3];
        float mu = a * (1.f / 256.f);
        float var = b * (1.f / 256.f) - mu * mu;
        mu_s[tid] = mu;
        rs_s[tid] = rsqrtf(fmaxf(var, 0.f) + 1e-6f);
    }
    __syncthreads();
#pragma unroll
    for (int nt = 0; nt < 4; ++nt) {
        int col = wn * 64 + nt * 16 + lm;
        float ga = gamma[col], be = beta[col];
#pragma unroll
        for (int mt = 0; mt < 4; ++mt)
#pragma unroll
            for (int r = 0; r < 4; ++r) {
                int rl = mt * 16 + quad * 4 + r;
                float hn = (acc[mt][nt][r] - mu_s[rl]) * rs_s[rl] * ga + be;
                g[(m0 + rl) * 256 + col] = (_Float16)gelu_(hn);
            }
    }
}

__global__ __launch_bounds__(256) void s5_k8_gemm_glu(const _Float16* __restrict__ A,
                                                      const _Float16* __restrict__ Wt,
                                                      const float* __restrict__ bias,
                                                      float* __restrict__ x,
                                                      _Float16* __restrict__ xh) {
    __shared__ _Float16 sA[128 * 64], sW[128 * 64];
    f32x4 acc[4][4];
    int m0 = blockIdx.x * 128, n0 = blockIdx.y * 128;
    gemm_core<128, 128, 2, 2>(A, Wt, sA, sW, m0, n0, acc);
    int tid = threadIdx.x, wid = tid >> 6, lane = tid & 63, lm = lane & 15, quad = lane >> 4;
    int wm = wid >> 1, wn = wid & 1;
#pragma unroll
    for (int mt = 0; mt < 4; ++mt)
#pragma unroll
        for (int nt = 0; nt < 4; ++nt) {
            int col = n0 + wn * 64 + nt * 16 + lm;
            float bv = bias[col];
#pragma unroll
            for (int r = 0; r < 4; ++r) {
                float v = acc[mt][nt][r] + bv;
                float pv = __shfl_xor(v, 1, 64);     // partner column (u1<->u2)
                if (!(lane & 1)) {
                    float gl = v * sigmoidf_(pv);
                    int row = m0 + wm * 64 + mt * 16 + quad * 4 + r;
                    int idx = row * 256 + (col >> 1);
                    float xn = x[idx] + gl;          // residual
                    x[idx] = xn;
                    xh[idx] = (_Float16)xn;
                }
            }
        }
}

__global__ __launch_bounds__(256) void s5_k9_gemm_out(const _Float16* __restrict__ A,
                                                      const _Float16* __restrict__ Wt,
                                                      const float* __restrict__ bout,
                                                      float* __restrict__ out) {
    __shared__ _Float16 sA[128 * 64], sW[64 * 64];
    f32x4 acc[2][4];
    int m0 = blockIdx.x * 128;
    gemm_core<128, 64, 4, 1>(A, Wt, sA, sW, m0, 0, acc);
    int tid = threadIdx.x, wid = tid >> 6, lane = tid & 63, lm = lane & 15, quad = lane >> 4;
#pragma unroll
    for (int mt = 0; mt < 2; ++mt)
#pragma unroll
        for (int nt = 0; nt < 4; ++nt) {
            int col = nt * 16 + lm;
            float bv = bout[col];
#pragma unroll
            for (int r = 0; r < 4; ++r) {
                int row = m0 + wid * 32 + mt * 16 + quad * 4 + r;
                out[row * 64 + col] = acc[mt][nt][r] + bv;
            }
        }
}

// --------------------------- workspace layout ------------------------------
constexpr size_t OFF_X    = 0;                         // fp32 L*256      33.6MB
constexpr size_t OFF_BU   = 33554432;                  // fp32 L*256 (reused: xs2 half + g half)
constexpr size_t OFF_H    = 67108864;                  // half L*256 (h; reused as xh)
constexpr size_t OFF_XSH  = 83886080;                  // half L*256 (local scans)
constexpr size_t OFF_WBU  = 100663296;                 // half 4*256*256
constexpr size_t OFF_WC   = OFF_WBU + 524288;
constexpr size_t OFF_WGLU = OFF_WC + 524288;           // half 4*512*256
constexpr size_t OFF_WOUT = OFF_WGLU + 1048576;        // half 64*256
constexpr size_t OFF_BGLU = OFF_WOUT + 32768;          // f32 4*512
constexpr size_t OFF_AR   = OFF_BGLU + 8192;
constexpr size_t OFF_AI   = OFF_AR + 2048;
constexpr size_t OFF_CBR  = OFF_AI + 2048;
constexpr size_t OFF_CBI  = OFF_CBR + 2048;
constexpr size_t OFF_ATR  = OFF_CBI + 2048;
constexpr size_t OFF_ATI  = OFF_ATR + 2048;
constexpr size_t OFF_ALP  = OFF_ATI + 2048;
constexpr size_t OFF_RALP = OFF_ALP + 2048;
constexpr size_t OFF_X0   = OFF_RALP + 2048;
constexpr size_t OFF_CARR = OFF_X0 + 1024;             // f32 256*128
constexpr size_t OFF_CARI = OFF_CARR + 131072;
constexpr size_t OFF_CINR = OFF_CARI + 131072;
constexpr size_t OFF_CINI = OFF_CINR + 131072;

extern "C" void kernel_launch(void* const* d_in, const int* in_sizes, int n_in,
                              void* d_out, int out_size, void* d_ws, size_t ws_size,
                              hipStream_t stream) {
    (void)in_sizes; (void)n_in; (void)out_size; (void)ws_size;
    const float* latent    = (const float*)d_in[0];
    const float* W_expand  = (const float*)d_in[1];
    const float* b_expand  = (const float*)d_in[2];
    const float* norm_s    = (const float*)d_in[3];
    const float* norm_b    = (const float*)d_in[4];
    const float* Lre       = (const float*)d_in[5];
    const float* Lim       = (const float*)d_in[6];
    const float* Bre       = (const float*)d_in[7];
    const float* Bim       = (const float*)d_in[8];
    const float* Cre       = (const float*)d_in[9];
    const float* Cim       = (const float*)d_in[10];
    const float* Dv        = (const float*)d_in[11];
    const float* lstep     = (const float*)d_in[12];
    const float* W1        = (const float*)d_in[13];
    const float* b1        = (const float*)d_in[14];
    const float* W2        = (const float*)d_in[15];
    const float* b2        = (const float*)d_in[16];
    const float* Wout      = (const float*)d_in[17];
    const float* bout      = (const float*)d_in[18];

    char* ws = (char*)d_ws;
    float*    x    = (float*)(ws + OFF_X);
    float*    Bu   = (float*)(ws + OFF_BU);
    _Float16* xs2  = (_Float16*)(ws + OFF_BU);                 // after k4, Bu region is free
    _Float16* gbuf = (_Float16*)(ws + OFF_BU + 16777216);
    _Float16* hbuf = (_Float16*)(ws + OFF_H);
    _Float16* xh   = (_Float16*)(ws + OFF_H);                  // h dead once k8 runs
    _Float16* xsh  = (_Float16*)(ws + OFF_XSH);
    _Float16* Wbu  = (_Float16*)(ws + OFF_WBU);
    _Float16* Wc   = (_Float16*)(ws + OFF_WC);
    _Float16* Wglu = (_Float16*)(ws + OFF_WGLU);
    _Float16* WoutT= (_Float16*)(ws + OFF_WOUT);
    float* bglu = (float*)(ws + OFF_BGLU);
    float* aR  = (float*)(ws + OFF_AR);
    float* aI  = (float*)(ws + OFF_AI);
    float* cbR = (float*)(ws + OFF_CBR);
    float* cbI = (float*)(ws + OFF_CBI);
    float* aTR = (float*)(ws + OFF_ATR);
    float* aTI = (float*)(ws + OFF_ATI);
    float* alp = (float*)(ws + OFF_ALP);
    float* ralp= (float*)(ws + OFF_RALP);
    float* x0  = (float*)(ws + OFF_X0);
    float* carR= (float*)(ws + OFF_CARR);
    float* carI= (float*)(ws + OFF_CARI);
    float* cinR= (float*)(ws + OFF_CINR);
    float* cinI= (float*)(ws + OFF_CINI);

    s5_k0a<<<1, 512, 0, stream>>>(Lre, Lim, lstep, aR, aI, cbR, cbI, aTR, aTI, alp, ralp);
    s5_k0b<<<256, 256, 0, stream>>>(Bre, Bim, Cre, Cim, W1, W2, b1, b2, Wout,
                                    cbR, cbI, alp, ralp, Wbu, Wc, Wglu, WoutT, bglu);
    s5_k0c<<<1, 256, 0, stream>>>(latent, W_expand, b_expand, x0);
    s5_k1_fill<<<8192, 256, 0, stream>>>(x0, x);

    for (int l = 0; l < 4; ++l) {
        s5_k2_ln<<<8192, 256, 0, stream>>>(x, norm_s + l * 256, norm_b + l * 256, hbuf);
        s5_k3_gemm_bu<<<dim3(256, 2), 256, 0, stream>>>(hbuf, Wbu + l * 65536, Bu);
        s5_k4_scan<<<NCH, 128, 0, stream>>>(Bu, aR + l * 128, aI + l * 128, xsh, carR, carI);
        s5_k5_carry<<<1, 128, 0, stream>>>(carR, carI, aTR + l * 128, aTI + l * 128, cinR, cinI);
        s5_k6_apply<<<NCH, 128, 0, stream>>>(xsh, cinR, cinI, aR + l * 128, aI + l * 128, xs2);
        s5_k7_gemm_c<<<512, 256, 0, stream>>>(xs2, Wc + l * 65536, hbuf, Dv + l * 256,
                                              norm_s + l * 256, norm_b + l * 256, gbuf);
        s5_k8_gemm_glu<<<dim3(256, 4), 256, 0, stream>>>(gbuf, Wglu + l * 131072,
                                                         bglu + l * 512, x, xh);
    }
    s5_k9_gemm_out<<<256, 256, 0, stream>>>(xh, WoutT, bout, (float*)d_out);
}